// Round 3
// baseline (987.948 us; speedup 1.0000x reference)
//
#include <hip/hip_runtime.h>
#include <stdint.h>

#define DEV __device__ __forceinline__

typedef unsigned short u16;
using f32x4  = __attribute__((ext_vector_type(4))) float;
using bf16x8 = __attribute__((ext_vector_type(8))) short;

constexpr int B_  = 4;
constexpr int L_  = 8192;
constexpr int D_  = 1024;
constexpr int M_  = B_ * L_;    // 32768
constexpr int K_  = D_;         // 1024
constexpr int CCH = 128;        // chunks per sequence
constexpr int TCH = L_ / CCH;   // 64 steps per chunk

constexpr int BKT = 32;         // k per K-tile
constexpr int NKT = K_ / BKT;   // 32 K-tiles

DEV u16 f2bf(float f) {
  uint32_t u = __float_as_uint(f);
  u += 0x7fffu + ((u >> 16) & 1u);
  return (u16)(u >> 16);
}
DEV float bf2f(u16 h) { return __uint_as_float(((uint32_t)h) << 16); }

DEV void async16(const void* g, const void* l) {
  __builtin_amdgcn_global_load_lds(
      (const __attribute__((address_space(1))) unsigned int*)g,
      (__attribute__((address_space(3))) unsigned int*)l, 16, 0, 0);
}

// ---------------- fp32 -> bf16 convert (n8 = count/8) ----------------
__global__ void cvt_kernel(const float* __restrict__ src, u16* __restrict__ dst, int n8) {
  int stride = gridDim.x * blockDim.x;
  for (int i = blockIdx.x * blockDim.x + threadIdx.x; i < n8; i += stride) {
    float4 a = reinterpret_cast<const float4*>(src)[2 * i];
    float4 b = reinterpret_cast<const float4*>(src)[2 * i + 1];
    union { u16 u[8]; uint4 v; } r;
    r.u[0] = f2bf(a.x); r.u[1] = f2bf(a.y); r.u[2] = f2bf(a.z); r.u[3] = f2bf(a.w);
    r.u[4] = f2bf(b.x); r.u[5] = f2bf(b.y); r.u[6] = f2bf(b.z); r.u[7] = f2bf(b.w);
    reinterpret_cast<uint4*>(dst)[i] = r.v;
  }
}

// ---------------- 256x256 GEMM mainloop, ring-2 counted-vmcnt pipeline -------
// C[256x256] = A[256xK] * B[256 rows of W]^T. 512 threads = 8 waves (2M x 4N).
// LDS per matrix: 2 buffers x [4 kgroups][256 rows][8 bf16] = 32 KiB.
// Pipeline: stage(t) issued at body t-2 (prologue t=0,1); body t waits
// vmcnt(4) (tile t landed, tile t+1's 4 loads/thread still in flight),
// raw s_barrier (no drain), ds_read, MFMA, barrier, then stage(t+2).
DEV void gemm_mainloop256(const u16* __restrict__ Ag, const u16* __restrict__ Bg,
                          int m0, int n0, u16* ldsA, u16* ldsB,
                          f32x4 acc[8][4]) {
  const int tid  = threadIdx.x;
  const int lane = tid & 63;
  const int wid  = tid >> 6;
  const int wr   = wid >> 2;    // 0..1
  const int wc   = wid & 3;     // 0..3

  auto stage = [&](int t, int b) {
#pragma unroll
    for (int u = 0; u < 2; ++u) {
      int sb  = wid * 64 + u * 512;      // wave-uniform slot base
      int s   = sb + lane;
      int row = s & 255, g = s >> 8;
      size_t koff = (size_t)t * BKT + g * 8;
      async16(Ag + (size_t)(m0 + row) * K_ + koff, ldsA + (size_t)b * 8192 + sb * 8);
      async16(Bg + (size_t)(n0 + row) * K_ + koff, ldsB + (size_t)b * 8192 + sb * 8);
    }
  };

  stage(0, 0);
  stage(1, 1);

  const int g    = lane >> 4;                    // k-group 0..3
  const int arow = wr * 128 + (lane & 15);
  const int brow = wc * 64  + (lane & 15);

  for (int t = 0; t < NKT; ++t) {
    asm volatile("s_waitcnt vmcnt(4)" ::: "memory");
    __builtin_amdgcn_s_barrier();
    asm volatile("" ::: "memory");

    const u16* ba = ldsA + (size_t)(t & 1) * 8192 + g * 2048 + arow * 8;
    const u16* bb = ldsB + (size_t)(t & 1) * 8192 + g * 2048 + brow * 8;
    bf16x8 af[8], bfr[4];
#pragma unroll
    for (int i = 0; i < 8; ++i) af[i]  = *reinterpret_cast<const bf16x8*>(ba + i * 128);
#pragma unroll
    for (int j = 0; j < 4; ++j) bfr[j] = *reinterpret_cast<const bf16x8*>(bb + j * 128);

    __builtin_amdgcn_s_setprio(1);
#pragma unroll
    for (int i = 0; i < 8; ++i)
#pragma unroll
      for (int j = 0; j < 4; ++j)
        acc[i][j] = __builtin_amdgcn_mfma_f32_16x16x32_bf16(af[i], bfr[j], acc[i][j], 0, 0, 0);
    __builtin_amdgcn_s_setprio(0);

    asm volatile("" ::: "memory");
    __builtin_amdgcn_s_barrier();
    asm volatile("" ::: "memory");

    if (t + 2 < NKT) stage(t + 2, t & 1);
  }
}

DEV int xcd_swizzle(int bid, int nwg) {   // nwg % 8 == 0 always here
  int cpx = nwg >> 3;
  return (bid & 7) * cpx + (bid >> 3);
}

// ---------------- projection GEMM: N = 3072 (dt | zpre | ya) ----------------
__global__ __launch_bounds__(512, 2) void gemm_proj_kernel(
    const u16* __restrict__ xb, const u16* __restrict__ Wcat,
    const float* __restrict__ b_dt, const float* __restrict__ b_lnz,
    const float* __restrict__ b_ya,
    u16* __restrict__ dtb, u16* __restrict__ zpb, u16* __restrict__ syab) {
  __shared__ __align__(16) u16 As[2][4][256][8];
  __shared__ __align__(16) u16 Bs[2][4][256][8];
  f32x4 acc[8][4] = {};

  constexpr int NT = 3 * D_ / 256;   // 12
  int swz = xcd_swizzle(blockIdx.x, gridDim.x);
  const int m0 = (swz / NT) * 256;
  const int n0 = (swz % NT) * 256;
  gemm_mainloop256(xb, Wcat, m0, n0, &As[0][0][0][0], &Bs[0][0][0][0], acc);

  const int tid = threadIdx.x, lane = tid & 63, wid = tid >> 6;
  const int wr = wid >> 2, wc = wid & 3;
  const int proj  = n0 >> 10;        // 0=dt 1=zpre 2=ya (256-block inside one proj)
  const int dbase = n0 & 1023;
  const float* bias = proj == 0 ? b_dt : (proj == 1 ? b_lnz : b_ya);
  u16* outp = proj == 0 ? dtb : (proj == 1 ? zpb : syab);
#pragma unroll
  for (int i = 0; i < 8; ++i) {
    int mr = m0 + wr * 128 + i * 16 + (lane >> 4) * 4;
#pragma unroll
    for (int j = 0; j < 4; ++j) {
      int nc = dbase + wc * 64 + j * 16 + (lane & 15);
      float bv = bias[nc];
#pragma unroll
      for (int r = 0; r < 4; ++r) {
        float v = acc[i][j][r] + bv;
        if (proj == 2) v = v / (1.f + __expf(-v));   // silu
        outp[(size_t)(mr + r) * D_ + nc] = f2bf(v);
      }
    }
  }
}

// ---------------- output GEMM: y = (h@w_y^T + b_y) * silu(ya) ----------------
__global__ __launch_bounds__(512, 2) void gemm_out_kernel(
    const u16* __restrict__ hb, const u16* __restrict__ Wyb,
    const float* __restrict__ b_y, const u16* __restrict__ syab,
    float* __restrict__ y) {
  __shared__ __align__(16) u16 As[2][4][256][8];
  __shared__ __align__(16) u16 Bs[2][4][256][8];
  f32x4 acc[8][4] = {};

  constexpr int NT = D_ / 256;       // 4
  int swz = xcd_swizzle(blockIdx.x, gridDim.x);
  const int m0 = (swz / NT) * 256;
  const int n0 = (swz % NT) * 256;
  gemm_mainloop256(hb, Wyb, m0, n0, &As[0][0][0][0], &Bs[0][0][0][0], acc);

  const int tid = threadIdx.x, lane = tid & 63, wid = tid >> 6;
  const int wr = wid >> 2, wc = wid & 3;
#pragma unroll
  for (int i = 0; i < 8; ++i) {
    int mr = m0 + wr * 128 + i * 16 + (lane >> 4) * 4;
#pragma unroll
    for (int j = 0; j < 4; ++j) {
      int nc = n0 + wc * 64 + j * 16 + (lane & 15);
      float bv = b_y[nc];
#pragma unroll
      for (int r = 0; r < 4; ++r) {
        float v = acc[i][j][r] + bv;
        float s = bf2f(syab[(size_t)(mr + r) * D_ + nc]);
        y[(size_t)(mr + r) * D_ + nc] = v * s;
      }
    }
  }
}

// ---------------- chunked scan: h_t = a_t h_{t-1} + z_t da_t ----------------
__global__ void scan1_kernel(const u16* __restrict__ dtb, const u16* __restrict__ zpb,
                             float* __restrict__ Ach, float* __restrict__ Bch) {
  const int b = blockIdx.x / CCH;
  const int c = blockIdx.x % CCH;
  const int d0 = threadIdx.x * 4;
  const size_t base = ((size_t)(b * L_ + c * TCH)) * D_ + d0;
  float h[4]  = {0.f, 0.f, 0.f, 0.f};
  float Ap[4] = {1.f, 1.f, 1.f, 1.f};
#pragma unroll 4
  for (int t = 0; t < TCH; ++t) {
    ushort4 du = *reinterpret_cast<const ushort4*>(dtb + base + (size_t)t * D_);
    ushort4 zu = *reinterpret_cast<const ushort4*>(zpb + base + (size_t)t * D_);
    const u16* dp = reinterpret_cast<const u16*>(&du);
    const u16* zz = reinterpret_cast<const u16*>(&zu);
#pragma unroll
    for (int q = 0; q < 4; ++q) {
      float dt = bf2f(dp[q]);
      float zv = bf2f(zz[q]);
      float a  = 1.f / (1.f + __expf(dt));    // sigmoid(-dt)
      float da = 1.f - a;                     // sigmoid(dt)
      float z  = 1.f / (1.f + __expf(-zv));   // sigmoid(zpre)
      h[q]  = a * h[q] + z * da;
      Ap[q] *= a;
    }
  }
  const size_t o = ((size_t)(b * CCH + c)) * D_ + d0;
  *reinterpret_cast<float4*>(Ach + o) = make_float4(Ap[0], Ap[1], Ap[2], Ap[3]);
  *reinterpret_cast<float4*>(Bch + o) = make_float4(h[0], h[1], h[2], h[3]);
}

__global__ void scan2_kernel(const float* __restrict__ Ach, const float* __restrict__ Bch,
                             const float* __restrict__ h0, float* __restrict__ Hin) {
  const int b = blockIdx.x;
  const int d0 = threadIdx.x * 4;
  float4 carry = *reinterpret_cast<const float4*>(h0 + d0);
  for (int c = 0; c < CCH; ++c) {
    const size_t o = ((size_t)(b * CCH + c)) * D_ + d0;
    *reinterpret_cast<float4*>(Hin + o) = carry;
    float4 A  = *reinterpret_cast<const float4*>(Ach + o);
    float4 Bv = *reinterpret_cast<const float4*>(Bch + o);
    carry.x = A.x * carry.x + Bv.x;
    carry.y = A.y * carry.y + Bv.y;
    carry.z = A.z * carry.z + Bv.z;
    carry.w = A.w * carry.w + Bv.w;
  }
}

__global__ void scan3_kernel(const u16* __restrict__ dtb, const u16* __restrict__ zpb,
                             const float* __restrict__ Hin, u16* __restrict__ hb) {
  const int b = blockIdx.x / CCH;
  const int c = blockIdx.x % CCH;
  const int d0 = threadIdx.x * 4;
  const size_t base = ((size_t)(b * L_ + c * TCH)) * D_ + d0;
  float4 hv = *reinterpret_cast<const float4*>(Hin + ((size_t)(b * CCH + c)) * D_ + d0);
  float h[4] = {hv.x, hv.y, hv.z, hv.w};
#pragma unroll 4
  for (int t = 0; t < TCH; ++t) {
    ushort4 du = *reinterpret_cast<const ushort4*>(dtb + base + (size_t)t * D_);
    ushort4 zu = *reinterpret_cast<const ushort4*>(zpb + base + (size_t)t * D_);
    const u16* dp = reinterpret_cast<const u16*>(&du);
    const u16* zz = reinterpret_cast<const u16*>(&zu);
    ushort4 ov;
    u16* op = reinterpret_cast<u16*>(&ov);
#pragma unroll
    for (int q = 0; q < 4; ++q) {
      float dt = bf2f(dp[q]);
      float zv = bf2f(zz[q]);
      float a  = 1.f / (1.f + __expf(dt));
      float da = 1.f - a;
      float z  = 1.f / (1.f + __expf(-zv));
      h[q] = a * h[q] + z * da;
      op[q] = f2bf(h[q]);
    }
    *reinterpret_cast<ushort4*>(hb + base + (size_t)t * D_) = ov;
  }
}

extern "C" void kernel_launch(void* const* d_in, const int* in_sizes, int n_in,
                              void* d_out, int out_size, void* d_ws, size_t ws_size,
                              hipStream_t stream) {
  const float* x     = (const float*)d_in[0];
  const float* w_lnz = (const float*)d_in[1];
  const float* b_lnz = (const float*)d_in[2];
  const float* w_dt  = (const float*)d_in[3];
  const float* b_dt  = (const float*)d_in[4];
  const float* w_y   = (const float*)d_in[5];
  const float* b_y   = (const float*)d_in[6];
  const float* w_ya  = (const float*)d_in[7];
  const float* b_ya  = (const float*)d_in[8];
  const float* h0    = (const float*)d_in[9];
  float* y = (float*)d_out;

  char* ws = (char*)d_ws;
  const size_t MB = 1024ull * 1024ull;
  u16*   xb   = (u16*)(ws);               // 64MB  bf16 x
  u16*   Wcat = (u16*)(ws + 64 * MB);     // 6MB   [w_dt; w_ln_z; w_ya]
  u16*   Wyb  = (u16*)(ws + 70 * MB);     // 2MB   w_y
  u16*   dtb  = (u16*)(ws + 72 * MB);     // 64MB
  u16*   zpb  = (u16*)(ws + 136 * MB);    // 64MB
  u16*   syab = (u16*)(ws + 200 * MB);    // 64MB  silu(ya)
  u16*   hb   = (u16*)(ws + 264 * MB);    // 64MB  h (bf16)
  float* Ach  = (float*)(ws + 328 * MB);  // 2MB
  float* Bch  = (float*)(ws + 330 * MB);  // 2MB
  float* Hin  = (float*)(ws + 332 * MB);  // 2MB

  // converts
  cvt_kernel<<<2048, 256, 0, stream>>>(x, xb, M_ * K_ / 8);
  cvt_kernel<<<256, 256, 0, stream>>>(w_dt,  Wcat,               K_ * D_ / 8);
  cvt_kernel<<<256, 256, 0, stream>>>(w_lnz, Wcat + 1024 * 1024, K_ * D_ / 8);
  cvt_kernel<<<256, 256, 0, stream>>>(w_ya,  Wcat + 2 * 1024 * 1024, K_ * D_ / 8);
  cvt_kernel<<<256, 256, 0, stream>>>(w_y,   Wyb,                K_ * D_ / 8);

  // fused 3-projection GEMM (256^2 tiles, 512 threads)
  gemm_proj_kernel<<<(M_ / 256) * (3 * D_ / 256), 512, 0, stream>>>(
      xb, Wcat, b_dt, b_lnz, b_ya, dtb, zpb, syab);

  // chunked scan
  scan1_kernel<<<B_ * CCH, 256, 0, stream>>>(dtb, zpb, Ach, Bch);
  scan2_kernel<<<B_, 256, 0, stream>>>(Ach, Bch, h0, Hin);
  scan3_kernel<<<B_ * CCH, 256, 0, stream>>>(dtb, zpb, Hin, hb);

  // output GEMM fused with silu gate
  gemm_out_kernel<<<(M_ / 256) * (D_ / 256), 512, 0, stream>>>(
      hb, Wyb, b_y, syab, y);
}

// Round 6
// 701.248 us; speedup vs baseline: 1.4088x; 1.4088x over previous
//
#include <hip/hip_runtime.h>
#include <stdint.h>

#define DEV __device__ __forceinline__

typedef unsigned short u16;
using f32x4  = __attribute__((ext_vector_type(4))) float;
using bf16x8 = __attribute__((ext_vector_type(8))) short;

constexpr int B_  = 4;
constexpr int L_  = 8192;
constexpr int D_  = 1024;
constexpr int M_  = B_ * L_;    // 32768
constexpr int K_  = D_;         // 1024
constexpr int CCH = 128;        // chunks per sequence
constexpr int TCH = L_ / CCH;   // 64 steps per chunk

DEV u16 f2bf(float f) {
  uint32_t u = __float_as_uint(f);
  u += 0x7fffu + ((u >> 16) & 1u);
  return (u16)(u >> 16);
}
DEV float bf2f(u16 h) { return __uint_as_float(((uint32_t)h) << 16); }

DEV void async16(const void* g, const void* l) {
  __builtin_amdgcn_global_load_lds(
      (const __attribute__((address_space(1))) unsigned int*)g,
      (__attribute__((address_space(3))) unsigned int*)l, 16, 0, 0);
}

// ---------------- fp32 -> bf16 convert (n8 = count/8) ----------------
__global__ void cvt_kernel(const float* __restrict__ src, u16* __restrict__ dst, int n8) {
  int stride = gridDim.x * blockDim.x;
  for (int i = blockIdx.x * blockDim.x + threadIdx.x; i < n8; i += stride) {
    float4 a = reinterpret_cast<const float4*>(src)[2 * i];
    float4 b = reinterpret_cast<const float4*>(src)[2 * i + 1];
    union { u16 u[8]; uint4 v; } r;
    r.u[0] = f2bf(a.x); r.u[1] = f2bf(a.y); r.u[2] = f2bf(a.z); r.u[3] = f2bf(a.w);
    r.u[4] = f2bf(b.x); r.u[5] = f2bf(b.y); r.u[6] = f2bf(b.z); r.u[7] = f2bf(b.w);
    reinterpret_cast<uint4*>(dst)[i] = r.v;
  }
}

// all 4 weight matrices in one launch (each 1024x1024 f32 -> bf16)
__global__ void cvt_w_kernel(const float* __restrict__ w0, const float* __restrict__ w1,
                             const float* __restrict__ w2, const float* __restrict__ w3,
                             u16* __restrict__ dcat, u16* __restrict__ d3) {
  constexpr int SEG = K_ * D_ / 8;   // 131072 per matrix (8-elem units)
  int stride = gridDim.x * blockDim.x;
  for (int i = blockIdx.x * blockDim.x + threadIdx.x; i < 4 * SEG; i += stride) {
    int seg = i / SEG, off = i - seg * SEG;
    const float* src = seg == 0 ? w0 : (seg == 1 ? w1 : (seg == 2 ? w2 : w3));
    u16* dst = seg == 3 ? d3 : (dcat + (size_t)seg * K_ * D_);
    float4 a = reinterpret_cast<const float4*>(src)[2 * off];
    float4 b = reinterpret_cast<const float4*>(src)[2 * off + 1];
    union { u16 u[8]; uint4 v; } r;
    r.u[0] = f2bf(a.x); r.u[1] = f2bf(a.y); r.u[2] = f2bf(a.z); r.u[3] = f2bf(a.w);
    r.u[4] = f2bf(b.x); r.u[5] = f2bf(b.y); r.u[6] = f2bf(b.z); r.u[7] = f2bf(b.w);
    reinterpret_cast<uint4*>(dst)[off] = r.v;
  }
}

// ---------------- 128x128 GEMM mainloop, row-major swizzled LDS --------------
// LDS per matrix: [128 rows][8 slots of 8 bf16] row-major (16KB), slot swizzled
// by  s_phys = s_logical ^ (row & 7)  (involution). Staging: lane-contiguous
// 16B loads (8 lanes cover one 128B row -> 16 cachelines/instr), with the
// inverse swizzle applied to the per-lane GLOBAL column (rule #21: linear LDS
// dest, pre-swizzled source). ds_read_b128 then lands 2-way on banks (free).
DEV void gemm_mainloop128(const u16* __restrict__ Ag, const u16* __restrict__ Bg,
                          int m0, int n0, u16* As, u16* Bs, f32x4 acc[4][4]) {
  const int tid  = threadIdx.x;
  const int lane = tid & 63;
  const int wid  = tid >> 6;
  const int wr   = wid >> 1;   // 0..1
  const int wc   = wid & 1;    // 0..1

  // per-thread staging coords (4 slots per matrix per K-tile)
  int srow[4], scol[4], sdst[4];
#pragma unroll
  for (int t = 0; t < 4; ++t) {
    int l = t * 256 + tid;           // 16B-slot index 0..1023
    int row = l >> 3, s = l & 7;
    srow[t] = row;
    scol[t] = (s ^ (row & 7)) * 8;   // pre-swizzled global column (bf16 units)
    sdst[t] = l * 8;                 // linear LDS dest (u16 units)
  }

  const int g0    = lane >> 4;              // k-group 0..3
  const int arow  = wr * 64 + (lane & 15);
  const int brow  = wc * 64 + (lane & 15);

  for (int kt = 0; kt < K_; kt += 64) {
#pragma unroll
    for (int t = 0; t < 4; ++t) {
      async16(Ag + (size_t)(m0 + srow[t]) * K_ + kt + scol[t], As + sdst[t]);
      async16(Bg + (size_t)(n0 + srow[t]) * K_ + kt + scol[t], Bs + sdst[t]);
    }
    __syncthreads();
#pragma unroll
    for (int kk = 0; kk < 2; ++kk) {
      const int g = kk * 4 + g0;            // 0..7
      bf16x8 af[4], bfr[4];
#pragma unroll
      for (int i = 0; i < 4; ++i) {
        int ra = arow + i * 16;
        int rb = brow + i * 16;
        af[i]  = *reinterpret_cast<const bf16x8*>(As + ra * 64 + ((g ^ (ra & 7)) * 8));
        bfr[i] = *reinterpret_cast<const bf16x8*>(Bs + rb * 64 + ((g ^ (rb & 7)) * 8));
      }
#pragma unroll
      for (int i = 0; i < 4; ++i)
#pragma unroll
        for (int j = 0; j < 4; ++j)
          acc[i][j] = __builtin_amdgcn_mfma_f32_16x16x32_bf16(af[i], bfr[j], acc[i][j], 0, 0, 0);
    }
    __syncthreads();
  }
}

DEV int xcd_swizzle(int bid, int nwg) {   // nwg % 8 == 0 always here
  int cpx = nwg >> 3;
  return (bid & 7) * cpx + (bid >> 3);
}

// ---------------- projection GEMM: N = 3072 (dt | zpre | ya) ----------------
__global__ __launch_bounds__(256, 4) void gemm_proj_kernel(
    const u16* __restrict__ xb, const u16* __restrict__ Wcat,
    const float* __restrict__ b_dt, const float* __restrict__ b_lnz,
    const float* __restrict__ b_ya,
    u16* __restrict__ dtb, u16* __restrict__ zpb, u16* __restrict__ syab) {
  __shared__ __align__(16) u16 As[128 * 64];
  __shared__ __align__(16) u16 Bs[128 * 64];
  f32x4 acc[4][4] = {};

  constexpr int NT = 3 * D_ / 128;   // 24 n-tiles
  int swz = xcd_swizzle(blockIdx.x, gridDim.x);
  const int m0 = (swz / NT) * 128;
  const int n0 = (swz % NT) * 128;
  gemm_mainloop128(xb, Wcat, m0, n0, As, Bs, acc);

  const int tid = threadIdx.x, lane = tid & 63, wid = tid >> 6;
  const int wr = wid >> 1, wc = wid & 1;
  const int proj  = n0 >> 10;        // 0=dt 1=zpre 2=ya
  const int dbase = n0 & 1023;
  const float* bias = proj == 0 ? b_dt : (proj == 1 ? b_lnz : b_ya);
  u16* outp = proj == 0 ? dtb : (proj == 1 ? zpb : syab);
#pragma unroll
  for (int i = 0; i < 4; ++i) {
    int mr = m0 + wr * 64 + i * 16 + (lane >> 4) * 4;
#pragma unroll
    for (int j = 0; j < 4; ++j) {
      int nc = dbase + wc * 64 + j * 16 + (lane & 15);
      float bv = bias[nc];
#pragma unroll
      for (int r = 0; r < 4; ++r) {
        float v = acc[i][j][r] + bv;
        if (proj == 2) v = v / (1.f + __expf(-v));   // silu
        outp[(size_t)(mr + r) * D_ + nc] = f2bf(v);
      }
    }
  }
}

// ---------------- output GEMM: y = (h@w_y^T + b_y) * silu(ya) ----------------
__global__ __launch_bounds__(256, 4) void gemm_out_kernel(
    const u16* __restrict__ hb, const u16* __restrict__ Wyb,
    const float* __restrict__ b_y, const u16* __restrict__ syab,
    float* __restrict__ y) {
  __shared__ __align__(16) u16 As[128 * 64];
  __shared__ __align__(16) u16 Bs[128 * 64];
  f32x4 acc[4][4] = {};

  constexpr int NT = D_ / 128;       // 8 n-tiles
  int swz = xcd_swizzle(blockIdx.x, gridDim.x);
  const int m0 = (swz / NT) * 128;
  const int n0 = (swz % NT) * 128;
  gemm_mainloop128(hb, Wyb, m0, n0, As, Bs, acc);

  const int tid = threadIdx.x, lane = tid & 63, wid = tid >> 6;
  const int wr = wid >> 1, wc = wid & 1;
#pragma unroll
  for (int i = 0; i < 4; ++i) {
    int mr = m0 + wr * 64 + i * 16 + (lane >> 4) * 4;
#pragma unroll
    for (int j = 0; j < 4; ++j) {
      int nc = n0 + wc * 64 + j * 16 + (lane & 15);
      float bv = b_y[nc];
#pragma unroll
      for (int r = 0; r < 4; ++r) {
        float v = acc[i][j][r] + bv;
        float s = bf2f(syab[(size_t)(mr + r) * D_ + nc]);
        y[(size_t)(mr + r) * D_ + nc] = v * s;
      }
    }
  }
}

// ---------------- chunked scan: h_t = a_t h_{t-1} + z_t da_t ----------------
__global__ void scan1_kernel(const u16* __restrict__ dtb, const u16* __restrict__ zpb,
                             float* __restrict__ Ach, float* __restrict__ Bch) {
  const int b = blockIdx.x / CCH;
  const int c = blockIdx.x % CCH;
  const int d0 = threadIdx.x * 4;
  const size_t base = ((size_t)(b * L_ + c * TCH)) * D_ + d0;
  float h[4]  = {0.f, 0.f, 0.f, 0.f};
  float Ap[4] = {1.f, 1.f, 1.f, 1.f};
#pragma unroll 4
  for (int t = 0; t < TCH; ++t) {
    ushort4 du = *reinterpret_cast<const ushort4*>(dtb + base + (size_t)t * D_);
    ushort4 zu = *reinterpret_cast<const ushort4*>(zpb + base + (size_t)t * D_);
    const u16* dp = reinterpret_cast<const u16*>(&du);
    const u16* zz = reinterpret_cast<const u16*>(&zu);
#pragma unroll
    for (int q = 0; q < 4; ++q) {
      float dt = bf2f(dp[q]);
      float zv = bf2f(zz[q]);
      float a  = 1.f / (1.f + __expf(dt));    // sigmoid(-dt)
      float da = 1.f - a;                     // sigmoid(dt)
      float z  = 1.f / (1.f + __expf(-zv));   // sigmoid(zpre)
      h[q]  = a * h[q] + z * da;
      Ap[q] *= a;
    }
  }
  const size_t o = ((size_t)(b * CCH + c)) * D_ + d0;
  *reinterpret_cast<float4*>(Ach + o) = make_float4(Ap[0], Ap[1], Ap[2], Ap[3]);
  *reinterpret_cast<float4*>(Bch + o) = make_float4(h[0], h[1], h[2], h[3]);
}

// scan2: thread per (b, d) -> 16 blocks of 256, coalesced loads
__global__ void scan2_kernel(const float* __restrict__ Ach, const float* __restrict__ Bch,
                             const float* __restrict__ h0, float* __restrict__ Hin) {
  const int b = blockIdx.x >> 2;
  const int d = (blockIdx.x & 3) * 256 + threadIdx.x;
  float carry = h0[d];
  for (int c = 0; c < CCH; ++c) {
    const size_t o = ((size_t)(b * CCH + c)) * D_ + d;
    Hin[o] = carry;
    carry = Ach[o] * carry + Bch[o];
  }
}

__global__ void scan3_kernel(const u16* __restrict__ dtb, const u16* __restrict__ zpb,
                             const float* __restrict__ Hin, u16* __restrict__ hb) {
  const int b = blockIdx.x / CCH;
  const int c = blockIdx.x % CCH;
  const int d0 = threadIdx.x * 4;
  const size_t base = ((size_t)(b * L_ + c * TCH)) * D_ + d0;
  float4 hv = *reinterpret_cast<const float4*>(Hin + ((size_t)(b * CCH + c)) * D_ + d0);
  float h[4] = {hv.x, hv.y, hv.z, hv.w};
#pragma unroll 4
  for (int t = 0; t < TCH; ++t) {
    ushort4 du = *reinterpret_cast<const ushort4*>(dtb + base + (size_t)t * D_);
    ushort4 zu = *reinterpret_cast<const ushort4*>(zpb + base + (size_t)t * D_);
    const u16* dp = reinterpret_cast<const u16*>(&du);
    const u16* zz = reinterpret_cast<const u16*>(&zu);
    ushort4 ov;
    u16* op = reinterpret_cast<u16*>(&ov);
#pragma unroll
    for (int q = 0; q < 4; ++q) {
      float dt = bf2f(dp[q]);
      float zv = bf2f(zz[q]);
      float a  = 1.f / (1.f + __expf(dt));
      float da = 1.f - a;
      float z  = 1.f / (1.f + __expf(-zv));
      h[q] = a * h[q] + z * da;
      op[q] = f2bf(h[q]);
    }
    *reinterpret_cast<ushort4*>(hb + base + (size_t)t * D_) = ov;
  }
}

extern "C" void kernel_launch(void* const* d_in, const int* in_sizes, int n_in,
                              void* d_out, int out_size, void* d_ws, size_t ws_size,
                              hipStream_t stream) {
  const float* x     = (const float*)d_in[0];
  const float* w_lnz = (const float*)d_in[1];
  const float* b_lnz = (const float*)d_in[2];
  const float* w_dt  = (const float*)d_in[3];
  const float* b_dt  = (const float*)d_in[4];
  const float* w_y   = (const float*)d_in[5];
  const float* b_y   = (const float*)d_in[6];
  const float* w_ya  = (const float*)d_in[7];
  const float* b_ya  = (const float*)d_in[8];
  const float* h0    = (const float*)d_in[9];
  float* y = (float*)d_out;

  char* ws = (char*)d_ws;
  const size_t MB = 1024ull * 1024ull;
  u16*   xb   = (u16*)(ws);               // 64MB  bf16 x
  u16*   Wcat = (u16*)(ws + 64 * MB);     // 6MB   [w_dt; w_ln_z; w_ya]
  u16*   Wyb  = (u16*)(ws + 70 * MB);     // 2MB   w_y
  u16*   dtb  = (u16*)(ws + 72 * MB);     // 64MB
  u16*   zpb  = (u16*)(ws + 136 * MB);    // 64MB
  u16*   syab = (u16*)(ws + 200 * MB);    // 64MB  silu(ya)
  u16*   hb   = (u16*)(ws + 264 * MB);    // 64MB  h (bf16)
  float* Ach  = (float*)(ws + 328 * MB);  // 2MB
  float* Bch  = (float*)(ws + 330 * MB);  // 2MB
  float* Hin  = (float*)(ws + 332 * MB);  // 2MB

  // converts
  cvt_kernel<<<2048, 256, 0, stream>>>(x, xb, M_ * K_ / 8);
  cvt_w_kernel<<<1024, 256, 0, stream>>>(w_dt, w_lnz, w_ya, w_y, Wcat, Wyb);

  // fused 3-projection GEMM (128^2 tiles)
  gemm_proj_kernel<<<(M_ / 128) * (3 * D_ / 128), 256, 0, stream>>>(
      xb, Wcat, b_dt, b_lnz, b_ya, dtb, zpb, syab);

  // chunked scan
  scan1_kernel<<<B_ * CCH, 256, 0, stream>>>(dtb, zpb, Ach, Bch);
  scan2_kernel<<<16, 256, 0, stream>>>(Ach, Bch, h0, Hin);
  scan3_kernel<<<B_ * CCH, 256, 0, stream>>>(dtb, zpb, Hin, hb);

  // output GEMM fused with silu gate
  gemm_out_kernel<<<(M_ / 128) * (D_ / 128), 256, 0, stream>>>(
      hb, Wyb, b_y, syab, y);
}